// Round 14
// baseline (275.599 us; speedup 1.0000x reference)
//
#include <hip/hip_runtime.h>
#include <math.h>

#define NPIX (2048*2048)
#define NBLOCKS 2048           // 8 blocks/CU resident via NATURAL VGPR=64 fit
#define CHUNK (NPIX/NBLOCKS)   // 2048 px per block
#define SPX 256
#define NGRP 4                 // 4 groups x 4 iters = 16 i-iters per wave

// global ws: NREP replicas of the 2305-float accumulator table (proven layout)
#define WS_T1 1024
#define WS_T2 2048
#define WS_F2 2304
#define WS_FLOATS 2305
#define NREP 32
#define RSTRIDE 2432
#define L_T1 1088
#define L_T2 2176
#define LDS_RED (2176 + 16*17)   // 2448 floats = 9792 B

typedef __attribute__((ext_vector_type(8))) short short8;
typedef __attribute__((ext_vector_type(4))) float f32x4;
typedef __attribute__((ext_vector_type(4))) unsigned int u32x4;

__device__ __forceinline__ unsigned int pk_trunc_bf16(float lo, float hi) {
    return __builtin_amdgcn_perm(__float_as_uint(hi), __float_as_uint(lo), 0x07060302u);
}
__device__ __forceinline__ unsigned int pk_lab(int lo, int hi) {
    return __builtin_amdgcn_perm((unsigned)hi, (unsigned)lo, 0x05040100u);
}
__device__ __forceinline__ unsigned int onehot2(unsigned int x, unsigned int tp) {
    const unsigned int a = x ^ tp;
    const unsigned int t = 0x40004000u - a;
    return t & 0x40004000u;
}

// asm-pinned 16B load (cannot be sunk/reordered) + counted wait & sched fence
// (unchanged from R11, which passes under LB(256,4)'s relaxed budget)
__device__ __forceinline__ void gld4(u32x4& d, const void* a) {
    asm volatile("global_load_dwordx4 %0, %1, off" : "=v"(d) : "v"(a));
}
#define ASM_WAITVM(n) do { asm volatile("s_waitcnt vmcnt(" #n ")" ::: "memory"); \
                           __builtin_amdgcn_sched_barrier(0); } while (0)

// LB(256,4) — the PROVEN config (R11). Occupancy comes from the natural
// VGPR=64 allocation: 512/64 = 8 waves/EU hardware limit, LDS 10KB -> 16
// blocks; with grid 2048 the dispatcher can co-schedule 8 blocks/CU.
// (R12/R13 lesson: LB(...,8)'s hard 64-reg cap + inline asm aborts; never
// constrain the allocator when the natural allocation already fits.)
__global__ __launch_bounds__(256, 4) void agg_mfma(
    const float* __restrict__ pred,
    const int*   __restrict__ kl,
    const int*   __restrict__ rl,
    float* __restrict__ ws)
{
    __shared__ union {
        float lab[2][1024];   // [buf][wv*256 + lane*4] : 2 x 1 KB per wave
        float red[LDS_RED];
    } sh;
    __shared__ float s_f2w[4];

    const int tid  = threadIdx.x;
    const int wv   = tid >> 6;
    const int lane = tid & 63;
    const int quad = lane >> 4;
    const int col  = lane & 15;
    const int c8   = col & 7;
    const bool lowcol = (col < 8);
    const unsigned int cpack = (unsigned)col * 0x00010001u;
    const unsigned int tps[4] = {cpack, cpack + 0x00100010u,
                                 cpack + 0x00200020u, cpack + 0x00300030u};
    const unsigned int hc = (col == 8) ? 0x3F803F80u : 0u;
    const short8 b2c = __builtin_bit_cast(short8, (u32x4){hc, hc, hc, hc});

    f32x4 acc0[4], acc1[4], acc2;
    #pragma unroll
    for (int s = 0; s < 4; ++s) {
        acc0[s] = (f32x4){0.f, 0.f, 0.f, 0.f};
        acc1[s] = (f32x4){0.f, 0.f, 0.f, 0.f};
    }
    acc2 = (f32x4){0.f, 0.f, 0.f, 0.f};
    float f2 = 0.f;

    const int P0 = blockIdx.x * CHUNK;
    const int pbase = (2 * wv) * 32 + quad * 8;   // = 64*wv + quad*8
    const float* pp = pred + (size_t)c8 * NPIX + P0 + pbase;

    // Cooperative label pipeline (proven R9/R11): ONE dwordx4 per 4-iter
    // group fetches the wave's full label block (1 KB unique, coalesced).
    const int* labbase = (lane & 32) ? rl : kl;
    const int* lco = labbase + P0 + ((lane >> 4) & 1) * SPX + 64 * wv
                   + (lane & 15) * 4;

    u32x4 R;
    gld4(R, lco);                       // labels group 0
    ASM_WAITVM(0);
    *(u32x4*)&sh.lab[0][wv * 256 + lane * 4] = R;
    gld4(R, lco + 2 * SPX);             // labels group 1 (in flight during g0)

    #pragma unroll 1
    for (int g = 0; g < NGRP; ++g) {
        if (g < NGRP - 1) {
            ASM_WAITVM(0);              // R = labels(g+1) landed
            *(u32x4*)&sh.lab[(g + 1) & 1][wv * 256 + lane * 4] = R;
            if (g < NGRP - 2) gld4(R, lco + 2 * (g + 2) * SPX);
        }
        const float* lb0 = sh.lab[g & 1] + wv * 256 + quad * 8;
        #pragma unroll
        for (int j = 0; j < 4; ++j) {   // (cs,i) order == R3's (s,i) order
            const int i = j & 1, cs = j >> 1;
            const float* lb = lb0 + cs * 64 + i * 32;
            const int4 ka = *(const int4*)(lb);
            const int4 kb = *(const int4*)(lb + 4);
            const int4 ra = *(const int4*)(lb + 128);
            const int4 rb = *(const int4*)(lb + 132);
            const int off = (2 * g + cs) * SPX + i * 32;
            const float4 pa  = *(const float4*)(pp + off);
            const float4 pb4 = *(const float4*)(pp + off + 4);

            const int   klv[8] = {ka.x, ka.y, ka.z, ka.w, kb.x, kb.y, kb.z, kb.w};
            const int   rlv[8] = {ra.x, ra.y, ra.z, ra.w, rb.x, rb.y, rb.z, rb.w};
            const float pv[8]  = {pa.x, pa.y, pa.z, pa.w, pb4.x, pb4.y, pb4.z, pb4.w};

            float pr[8];
            #pragma unroll
            for (int jj = 0; jj < 8; ++jj) {
                pr[jj] = (rlv[jj] > 0) ? pv[jj] : 0.f;
                f2 = fmaf(pr[jj], pr[jj], f2);   // exact f32 sum of pr^2
            }
            unsigned int b1p[4], kp4[4], rp4[4];
            #pragma unroll
            for (int q = 0; q < 4; ++q) {
                const int j0 = 2 * q, j1 = 2 * q + 1;
                const unsigned int plo = pk_trunc_bf16(pv[j0], pv[j1]);
                const unsigned int phi = pk_trunc_bf16(pr[j0], pr[j1]);
                b1p[q] = lowcol ? plo : phi;
                kp4[q] = pk_lab(klv[j0], klv[j1]);
                rp4[q] = pk_lab(rlv[j0], rlv[j1]);
            }
            const short8 b1 = __builtin_bit_cast(short8,
                (u32x4){b1p[0], b1p[1], b1p[2], b1p[3]});

            #pragma unroll
            for (int t = 0; t < 4; ++t) {        // T0 + T1 share ohk
                u32x4 oh;
                #pragma unroll
                for (int q = 0; q < 4; ++q) oh[q] = onehot2(kp4[q], tps[t]);
                const short8 ak = __builtin_bit_cast(short8, oh);
                acc0[t] = __builtin_amdgcn_mfma_f32_16x16x32_bf16(ak, b1,  acc0[t], 0, 0, 0);
                acc1[t] = __builtin_amdgcn_mfma_f32_16x16x32_bf16(ak, b2c, acc1[t], 0, 0, 0);
            }
            u32x4 alo, bhi;                      // T2 radix: 1 MFMA
            #pragma unroll
            for (int q = 0; q < 4; ++q) {
                alo[q] = onehot2(rp4[q] & 0x000F000Fu, cpack);
                bhi[q] = onehot2((rp4[q] >> 4) & 0x00030003u, cpack);
            }
            acc2 = __builtin_amdgcn_mfma_f32_16x16x32_bf16(
                __builtin_bit_cast(short8, alo), __builtin_bit_cast(short8, bhi),
                acc2, 0, 0, 0);
        }
    }

    // --- f2: wave shuffle reduce
    #pragma unroll
    for (int off = 32; off > 0; off >>= 1) f2 += __shfl_down(f2, off, 64);
    if (lane == 0) s_f2w[wv] = f2;

    // --- cross-wave reduce, phased RMW (red unions over lab; barrier first)
    __syncthreads();
    for (int w = 0; w < 4; ++w) {
        if (wv == w) {
            #pragma unroll
            for (int t = 0; t < 4; ++t)
                #pragma unroll
                for (int i = 0; i < 4; ++i) {
                    const int l = t * 16 + quad * 4 + i;
                    const int a0 = l * 17 + col;
                    const int a1 = L_T1 + l * 17 + col;
                    if (w == 0) { sh.red[a0] = acc0[t][i]; sh.red[a1] = acc1[t][i]; }
                    else        { sh.red[a0] += acc0[t][i]; sh.red[a1] += acc1[t][i]; }
                }
            #pragma unroll
            for (int i = 0; i < 4; ++i) {
                const int a2 = L_T2 + (quad * 4 + i) * 17 + col;
                if (w == 0) sh.red[a2] = acc2[i]; else sh.red[a2] += acc2[i];
            }
        }
        __syncthreads();
    }
    float* wsr = ws + (size_t)(blockIdx.x & (NREP - 1)) * RSTRIDE;
    if (tid == 0)
        atomicAdd(&wsr[WS_F2], s_f2w[0] + s_f2w[1] + s_f2w[2] + s_f2w[3]);
    for (int idx = tid; idx < 2304; idx += 256) {
        int a;
        if (idx < 1024)      a = (idx >> 4) * 17 + (idx & 15);
        else if (idx < 2048) a = L_T1 + ((idx - 1024) >> 4) * 17 + (idx & 15);
        else                 a = L_T2 + ((idx - 2048) >> 4) * 17 + (idx & 15);
        atomicAdd(&wsr[idx], sh.red[a]);
    }
}

// fold NREP replicas into replica 0 (L2-hot)
__global__ __launch_bounds__(256) void agg_reduce(float* __restrict__ ws)
{
    const int i = blockIdx.x * 256 + threadIdx.x;
    if (i >= WS_FLOATS) return;
    float s = ws[i];
    #pragma unroll 4
    for (int r = 1; r < NREP; ++r) s += ws[i + (size_t)r * RSTRIDE];
    ws[i] = s;
}

__global__ __launch_bounds__(64) void agg_final(const float* __restrict__ ws,
                                                float* __restrict__ out)
{
    const int l = threadIdx.x;
    const float* t0 = ws + l * 16;
    const float pck = 0.5f  * ws[WS_T1 + l * 16 + 8];
    const float pcr = 0.25f * ws[WS_T2 + (l & 15) * 16 + (l >> 4)];

    float corr = 0.f;
    if (l > 0) {
        #pragma unroll
        for (int c = 0; c < 8; ++c) {
            const float seg = 0.5f * t0[c];
            const float T   = 0.5f * t0[8 + c];
            const float gk  = seg / (pck + 1.f);
            corr += gk * (gk * pck - 2.f * T);
        }
    }
    const float rcard = (l > 0) ? pcr : 0.f;
    float S = pcr / (rcard + 1.f);
    int mx = (pcr > 0.5f) ? l : 0;
    float f2 = (l == 0) ? 0.5f * ws[WS_F2] : 0.f;

    #pragma unroll
    for (int off = 32; off > 0; off >>= 1) {
        f2   += __shfl_down(f2, off, 64);
        corr += __shfl_down(corr, off, 64);
        S    += __shfl_down(S, off, 64);
        mx    = max(mx, __shfl_down(mx, off, 64));
    }
    if (l == 0) {
        const float SS = f2 + corr;
        float D = sqrtf(fmaxf(SS, 0.f)) - 0.5f;
        D = fmaxf(D, 0.f);
        out[0] = logf(D * D + 1.f) * S / (float)max(mx, 1);
    }
}

extern "C" void kernel_launch(void* const* d_in, const int* in_sizes, int n_in,
                              void* d_out, int out_size, void* d_ws, size_t ws_size,
                              hipStream_t stream) {
    const float* pred = (const float*)d_in[0];
    const int* kl = (const int*)d_in[3];
    const int* rl = (const int*)d_in[4];
    float* ws = (float*)d_ws;

    hipMemsetAsync(d_ws, 0, (size_t)NREP * RSTRIDE * sizeof(float), stream);
    agg_mfma<<<NBLOCKS, 256, 0, stream>>>(pred, kl, rl, ws);
    agg_reduce<<<(WS_FLOATS + 255) / 256, 256, 0, stream>>>(ws);
    agg_final<<<1, 64, 0, stream>>>(ws, (float*)d_out);
}